// Round 14
// baseline (267.282 us; speedup 1.0000x reference)
//
#include <hip/hip_runtime.h>

typedef _Float16 h2 __attribute__((ext_vector_type(2)));
typedef _Float16 h8 __attribute__((ext_vector_type(8)));
typedef float f4 __attribute__((ext_vector_type(4)));

#define BB 256
#define II 1152
#define QQ 8
#define JJ 10
#define PP 16

#define BT 16            // b per block (256 thr = 4 waves; 16 b x 16 p roles)
#define IT 8             // i per block (2 per wave)
#define NBT (BB / BT)    // 16
#define NIT (II / IT)    // 144
#define XRH 72           // halfs per staged-x b-row (64 + 8 pad)
#define VHR 168          // halfs per vh b-row (160 + 8 pad -> bank-spread)
#define XTQ 17           // xT q-stride (16 + 1 pad)
#define XTI 136          // xT il-stride (8*17)

#define NW (JJ * II * PP * QQ)   // 1474560
#define NX (BB * II * QQ)        // 2359296
#define NS (BB * JJ * PP)        // 40960
#define JSTRIDE ((size_t)II * PP * QQ)  // halfs per j in W / Wt
#define LOG2E 1.4426950408889634f

// ---------------------------------------------------------------------------
// 16-lane row sum via DPP (VALU pipe only).
// ---------------------------------------------------------------------------
template <int CTRL>
__device__ __forceinline__ float dpp_add(float v) {
    int s = __builtin_bit_cast(int, v);
    int t = __builtin_amdgcn_update_dpp(0, s, CTRL, 0xF, 0xF, true);
    return v + __builtin_bit_cast(float, t);
}
__device__ __forceinline__ float row_sum16(float v) {
    v = dpp_add<0xB1>(v);   // xor1
    v = dpp_add<0x4E>(v);   // xor2
    v = dpp_add<0x124>(v);  // row_ror:4
    v = dpp_add<0x128>(v);  // row_ror:8
    return v;
}
// xor-16 exchange (quad0<->1 and quad2<->3), LDS-pipe swizzle, 1 inst
__device__ __forceinline__ float swz_xor16(float v) {
    int s = __builtin_bit_cast(int, v);
    return __builtin_bit_cast(float, __builtin_amdgcn_ds_swizzle(s, 0x401F));
}

// ---------------------------------------------------------------------------
// prep: Wh=[j][i][p][q] f16, Wt=[j][i][q][p] f16 (transpose), Xh f16; zero S.
// ---------------------------------------------------------------------------
__global__ __launch_bounds__(256) void prep_kernel(
    const float* __restrict__ X, const float* __restrict__ W,
    _Float16* __restrict__ Xh, _Float16* __restrict__ Wh,
    _Float16* __restrict__ Wt, float* __restrict__ S)
{
    const int g = blockIdx.x * 256 + threadIdx.x;
    const int stride = gridDim.x * 256;
    typedef _Float16 h4 __attribute__((ext_vector_type(4)));
    for (int k = g; k < NW / 4; k += stride) {
        const float4 f = ((const float4*)W)[k];
        h4 o = { (_Float16)f.x, (_Float16)f.y, (_Float16)f.z, (_Float16)f.w };
        ((h4*)Wh)[k] = o;
    }
    // transpose: out idx k -> p=k&15, q=(k>>4)&7, ji=k>>7; in = (ji*16+p)*8+q
    for (int k = g; k < NW; k += stride) {
        const int p = k & 15, q = (k >> 4) & 7, ji = k >> 7;
        Wt[k] = (_Float16)W[((size_t)ji * 16 + p) * 8 + q];
    }
    for (int k = g; k < NX / 4; k += stride) {
        const float4 f = ((const float4*)X)[k];
        h4 o = { (_Float16)f.x, (_Float16)f.y, (_Float16)f.z, (_Float16)f.w };
        ((h4*)Xh)[k] = o;
    }
    const float4 z = {0.f, 0.f, 0.f, 0.f};
    for (int k = g; k < 3 * NS / 4; k += stride) ((float4*)S)[k] = z;
}

// ---------------------------------------------------------------------------
// s0 via MFMA (unchanged from R13 — layouts verified by passing result).
// ---------------------------------------------------------------------------
__global__ __launch_bounds__(256) void s0_mfma_kernel(
    const _Float16* __restrict__ Xh, const _Float16* __restrict__ Wh,
    float* __restrict__ S0)
{
    const int wid  = blockIdx.x * 4 + (threadIdx.x >> 6);  // 0..1279
    const int lane = threadIdx.x & 63;
    const int bt  = wid / 80;
    const int rem = wid % 80;
    const int j   = rem >> 3;
    const int kc  = rem & 7;
    const int b0  = bt * 16;
    const int m    = lane & 15;
    const int quad = lane >> 4;
    const int ib   = kc * 144;

    const _Float16* ax = Xh + ((size_t)(b0 + m) * II + ib + quad) * QQ;
    const _Float16* bw = Wh + (((size_t)j * II + ib + quad) * PP + m) * QQ;

    f4 acc = {0.f, 0.f, 0.f, 0.f};
    for (int t = 0; t < 36; ++t) {
        const h8 a = *(const h8*)ax;
        const h8 b = *(const h8*)bw;
        acc = __builtin_amdgcn_mfma_f32_16x16x32_f16(a, b, acc, 0, 0, 0);
        ax += 4 * QQ;
        bw += (size_t)4 * PP * QQ;
    }
#pragma unroll
    for (int r = 0; r < 4; ++r)
        atomicAdd(&S0[((size_t)(b0 + quad * 4 + r) * JJ + j) * PP + m], 0.1f * acc[r]);
}

// ---------------------------------------------------------------------------
// MFMA routing pass (R=1,2). Block = 256 thr = 4 waves; wave w owns i-pair
// (i0+2w, i0+2w+1) for 16 b. Straight-line, one barrier.
//
// GEMM_u (per j): u[(i,q),b] = sum_p Wt[j,i,q,p] * vh[b,j,p]
//   mfma_16x16x32: A lane(m=lane&15=(i_sub,q), quad): 8 halfs k=p=quad*8+r ->
//   Wt[j, i, q, p-range] contiguous (global). B lane(n=b=lane&15, quad):
//   vh[b,j,p-range] (LDS); quads 2-3 zeroed (K pad 16->32).
//   D: col=b, row=quad*4+r=(i_sub,q). logit = sum_r D[r]*xT[i,q(r),b], then
//   + swz_xor16 partner (q 0-3 + q 4-7). All verified-by-s0 layouts.
// softmax per lane (10 regs), c -> f16 splat.
// GEMM_c (per j): s[b,p] += sum_{i,q} (c[b,j,i]*x[b,i,q]) * W[j,i,p,q]
//   K layout: k0-7 = i0, k16-23 = i1, zeros at k8-15/24-31 via B -> each
//   quad-pair uses the c it computed (no cross-lane move, no 2nd barrier).
//   A lane(b, quad): c_splat * xs[b, i(quad>>1)]; B lane(p, quad):
//   Wh[j, i(quad>>1), p, :] (global), zeroed on odd quads. D: col=p, row=b.
// ---------------------------------------------------------------------------
template <int R>
__global__ __launch_bounds__(256, 4) void pass_kernel(
    const _Float16* __restrict__ Xh,  // [B][I][Q] f16
    const _Float16* __restrict__ Wh,  // [J][I][P][Q] f16
    const _Float16* __restrict__ Wt,  // [J][I][Q][P] f16
    const float* __restrict__ Sprev,  // [B][J][P]
    float* __restrict__ V0,           // v0 raw (R1 writes it==0, R2 reads)
    float* __restrict__ Sout)         // [B][J][P] pre-zeroed accumulator
{
    __shared__ _Float16 xs[BT * XRH];   // 2.25 KB  [b][i*8+q]
    __shared__ float    xT[IT * XTI];   // 4.25 KB  [il][q*17+b] f32
    __shared__ _Float16 vh[BT * VHR];   // 5.25 KB  [b][j*16+p] (v*log2e, f16)

    const int bt = blockIdx.x & (NBT - 1);
    const int it = blockIdx.x >> 4;
    const int b0 = bt * BT;
    const int i0 = it * IT;
    const int tid = threadIdx.x;

    // ---- stage xs (h8-coalesced, 128 thr)
    if (tid < 128) {
        const int xb = tid >> 3, xr = tid & 7;
        *(h8*)(xs + xb * XRH + xr * 8) =
            *(const h8*)(Xh + ((size_t)(b0 + xb) * II + i0) * QQ + xr * 8);
    }
    // ---- stage xT (f32, scalar gather; once per block)
#pragma unroll
    for (int r = 0; r < 4; ++r) {
        const int idx = tid + r * 256;            // 0..1023
        const int b = idx & 15, q = (idx >> 4) & 7, il = idx >> 7;
        xT[il * XTI + q * XTQ + b] =
            (float)Xh[((size_t)(b0 + b) * II + i0 + il) * QQ + q];
    }
    // ---- build vh: thread (b_l, p); DPP squash of Sprev
    {
        const int b_l = tid >> 4, p = tid & 15;
        const int b = b0 + b_l;
#pragma unroll
        for (int j = 0; j < JJ; ++j) {
            const float sp = Sprev[((size_t)b * JJ + j) * PP + p];
            const float n2 = row_sum16(sp * sp);
            const float sc = n2 * __builtin_amdgcn_rcpf(1.0f + n2)
                                * __builtin_amdgcn_rsqf(n2 + 1e-7f);
            float v = sp * sc;
            if (R == 1) {
                if (it == 0) V0[((size_t)b * JJ + j) * PP + p] = v;
            } else {
                v += V0[((size_t)b * JJ + j) * PP + p];
            }
            vh[b_l * VHR + j * 16 + p] = (_Float16)(v * LOG2E);
        }
    }
    __syncthreads();

    const int lane = tid & 63;
    const int wv   = tid >> 6;          // wave -> i-pair
    const int quad = lane >> 4;
    const int l15  = lane & 15;
    const h8 hz = {(_Float16)0, (_Float16)0, (_Float16)0, (_Float16)0,
                   (_Float16)0, (_Float16)0, (_Float16)0, (_Float16)0};

    // ---- GEMM_u -> logits
    // x values for extraction: b=l15, il=2wv+(quad>>1), q=(quad&1)*4+r
    const int il = 2 * wv + (quad >> 1);
    float xv0, xv1, xv2, xv3;
    {
        const float* xp = xT + il * XTI + ((quad & 1) * 4) * XTQ + l15;
        xv0 = xp[0]; xv1 = xp[XTQ]; xv2 = xp[2 * XTQ]; xv3 = xp[3 * XTQ];
    }
    // A base: m=l15 -> i_sub=m>>3, q=m&7; quad&1 selects p-halves
    const int iA = i0 + 2 * wv + (l15 >> 3);
    const _Float16* abase = Wt + ((size_t)iA * QQ + (l15 & 7)) * PP + (quad & 1) * 8;
    const _Float16* vbase = vh + l15 * VHR + (quad & 1) * 8;

    float lg[JJ];
#pragma unroll
    for (int j = 0; j < JJ; ++j) {
        const h8 a  = *(const h8*)(abase + (size_t)j * JSTRIDE);
        h8 bv = *(const h8*)(vbase + j * 16);
        if (quad >= 2) bv = hz;                       // zero K=16..31
        f4 acc = {0.f, 0.f, 0.f, 0.f};
        acc = __builtin_amdgcn_mfma_f32_16x16x32_f16(a, bv, acc, 0, 0, 0);
        const float part = acc[0] * xv0 + acc[1] * xv1 + acc[2] * xv2 + acc[3] * xv3;
        lg[j] = part + swz_xor16(part);               // q0-3 + q4-7
    }

    // ---- softmax over j (per lane; lane owns (b=l15, i=il))
    float e[JJ];
#pragma unroll
    for (int j = 0; j < JJ; ++j) e[j] = __builtin_amdgcn_exp2f(lg[j]);
    float s01 = e[0] + e[1], s23 = e[2] + e[3], s45 = e[4] + e[5],
          s67 = e[6] + e[7], s89 = e[8] + e[9];
    const float sum = ((s01 + s23) + (s45 + s67)) + s89;
    const float inv = __builtin_amdgcn_rcpf(sum);

    // ---- GEMM_c -> s atomics
    const int ig = i0 + 2 * wv + (quad >> 1);        // i for this quad-pair
    const h8 x8 = *(const h8*)(xs + l15 * XRH + (2 * wv + (quad >> 1)) * 8);
    const _Float16* bbase = Wh + ((size_t)ig * PP + l15) * QQ;

#pragma unroll
    for (int j = 0; j < JJ; ++j) {
        const _Float16 ch = (_Float16)(e[j] * inv);  // c, f16
        const h8 cs8 = {ch, ch, ch, ch, ch, ch, ch, ch};
        const h8 a2 = x8 * cs8;                      // 4x v_pk_mul_f16
        h8 b2 = *(const h8*)(bbase + (size_t)j * JSTRIDE);
        if (quad & 1) b2 = hz;                       // zeros at k8-15 / k24-31
        f4 acc = {0.f, 0.f, 0.f, 0.f};
        acc = __builtin_amdgcn_mfma_f32_16x16x32_f16(a2, b2, acc, 0, 0, 0);
#pragma unroll
        for (int r = 0; r < 4; ++r)
            atomicAdd(&Sout[((size_t)(b0 + quad * 4 + r) * JJ + j) * PP + l15], acc[r]);
    }
}

// ---------------------------------------------------------------------------
// final output squash (fp32 precise)
// ---------------------------------------------------------------------------
__global__ __launch_bounds__(256) void squash_out_kernel(const float* __restrict__ S,
                                                         float* __restrict__ V)
{
    const int idx = blockIdx.x * blockDim.x + threadIdx.x;  // (b*J + j)
    if (idx >= BB * JJ) return;
    const float4* sp = (const float4*)(S + idx * PP);
    float4 a = sp[0], b4 = sp[1], c4 = sp[2], d4 = sp[3];
    float s2 = a.x * a.x + a.y * a.y + a.z * a.z + a.w * a.w +
               b4.x * b4.x + b4.y * b4.y + b4.z * b4.z + b4.w * b4.w +
               c4.x * c4.x + c4.y * c4.y + c4.z * c4.z + c4.w * c4.w +
               d4.x * d4.x + d4.y * d4.y + d4.z * d4.z + d4.w * d4.w;
    const float scale = s2 / (1.0f + s2) / sqrtf(s2 + 1e-7f);
    a.x *= scale; a.y *= scale; a.z *= scale; a.w *= scale;
    b4.x *= scale; b4.y *= scale; b4.z *= scale; b4.w *= scale;
    c4.x *= scale; c4.y *= scale; c4.z *= scale; c4.w *= scale;
    d4.x *= scale; d4.y *= scale; d4.z *= scale; d4.w *= scale;
    float4* vp = (float4*)(V + idx * PP);
    vp[0] = a; vp[1] = b4; vp[2] = c4; vp[3] = d4;
}

extern "C" void kernel_launch(void* const* d_in, const int* in_sizes, int n_in,
                              void* d_out, int out_size, void* d_ws, size_t ws_size,
                              hipStream_t stream)
{
    const float* X = (const float*)d_in[0];  // [256][1152][8]
    const float* W = (const float*)d_in[1];  // [10][1152][16][8]
    float* out = (float*)d_out;              // [256][10][16]

    _Float16* Xh = (_Float16*)d_ws;          // NX halfs
    _Float16* Wh = Xh + NX;                  // NW halfs
    _Float16* Wt = Wh + NW;                  // NW halfs (transposed copy)
    float* S0 = (float*)(Wt + NW);           // NS floats
    float* S1 = S0 + NS;
    float* S2 = S1 + NS;
    float* v0 = S2 + NS;                     // NS floats; total ~11.3 MB

    const int grid = NBT * NIT;              // 2304 blocks of 256 threads

    prep_kernel<<<1024, 256, 0, stream>>>(X, W, Xh, Wh, Wt, S0);
    s0_mfma_kernel<<<320, 256, 0, stream>>>(Xh, Wh, S0);
    pass_kernel<1><<<grid, 256, 0, stream>>>(Xh, Wh, Wt, S0, v0, S1);
    pass_kernel<2><<<grid, 256, 0, stream>>>(Xh, Wh, Wt, S1, v0, S2);
    squash_out_kernel<<<10, 256, 0, stream>>>(S2, out);
}

// Round 15
// 154.669 us; speedup vs baseline: 1.7281x; 1.7281x over previous
//
#include <hip/hip_runtime.h>

typedef _Float16 h2 __attribute__((ext_vector_type(2)));
typedef _Float16 h8 __attribute__((ext_vector_type(8)));
typedef float f4 __attribute__((ext_vector_type(4)));

#define BB 256
#define II 1152
#define QQ 8
#define JJ 10
#define PP 16

#define BT 32            // b per block: 2 per thread (256 thr = 16 bg x 16 p)
#define IT 8             // i per block
#define NBT (BB / BT)    // 8
#define NIT (II / IT)    // 144
#define XRH 72           // halfs per staged-x b-row (64 + 8 pad)
#define WTILE (IT * PP * QQ)     // 1024 halfs per j in the LDS W-tile

#define NW (JJ * II * PP * QQ)   // 1474560
#define NX (BB * II * QQ)        // 2359296
#define NS (BB * JJ * PP)        // 40960
#define LOG2E 1.4426950408889634f

// ---------------------------------------------------------------------------
// 16-lane row sum via DPP (VALU pipe only).
// ---------------------------------------------------------------------------
template <int CTRL>
__device__ __forceinline__ float dpp_add(float v) {
    int s = __builtin_bit_cast(int, v);
    int t = __builtin_amdgcn_update_dpp(0, s, CTRL, 0xF, 0xF, true);
    return v + __builtin_bit_cast(float, t);
}
__device__ __forceinline__ float row_sum16(float v) {
    v = dpp_add<0xB1>(v);   // xor1
    v = dpp_add<0x4E>(v);   // xor2
    v = dpp_add<0x124>(v);  // row_ror:4
    v = dpp_add<0x128>(v);  // row_ror:8
    return v;
}

// 8-element f16 dot with fp32 accumulate: 4 x v_dot2_f32_f16.
__device__ __forceinline__ float dot8(h8 w, h8 x) {
    h2 w0 = __builtin_shufflevector(w, w, 0, 1), w1 = __builtin_shufflevector(w, w, 2, 3);
    h2 w2 = __builtin_shufflevector(w, w, 4, 5), w3 = __builtin_shufflevector(w, w, 6, 7);
    h2 x0 = __builtin_shufflevector(x, x, 0, 1), x1 = __builtin_shufflevector(x, x, 2, 3);
    h2 x2 = __builtin_shufflevector(x, x, 4, 5), x3 = __builtin_shufflevector(x, x, 6, 7);
    float acc = __builtin_amdgcn_fdot2(w0, x0, 0.0f, false);
    acc = __builtin_amdgcn_fdot2(w1, x1, acc, false);
    acc = __builtin_amdgcn_fdot2(w2, x2, acc, false);
    acc = __builtin_amdgcn_fdot2(w3, x3, acc, false);
    return acc;
}

// ---------------------------------------------------------------------------
// prep: W,X fp32 -> f16; zero S0/S1/S2 (contiguous). (Wt transpose dropped.)
// ---------------------------------------------------------------------------
__global__ __launch_bounds__(256) void prep_kernel(
    const float* __restrict__ X, const float* __restrict__ W,
    _Float16* __restrict__ Xh, _Float16* __restrict__ Wh,
    float* __restrict__ S)   // 3*NS floats
{
    const int g = blockIdx.x * 256 + threadIdx.x;
    const int stride = gridDim.x * 256;
    typedef _Float16 h4 __attribute__((ext_vector_type(4)));
    for (int k = g; k < NW / 4; k += stride) {
        const float4 f = ((const float4*)W)[k];
        h4 o = { (_Float16)f.x, (_Float16)f.y, (_Float16)f.z, (_Float16)f.w };
        ((h4*)Wh)[k] = o;
    }
    for (int k = g; k < NX / 4; k += stride) {
        const float4 f = ((const float4*)X)[k];
        h4 o = { (_Float16)f.x, (_Float16)f.y, (_Float16)f.z, (_Float16)f.w };
        ((h4*)Xh)[k] = o;
    }
    const float4 z = {0.f, 0.f, 0.f, 0.f};
    for (int k = g; k < 3 * NS / 4; k += stride) ((float4*)S)[k] = z;
}

// ---------------------------------------------------------------------------
// s0 via MFMA (verified in R13): s0 = 0.1 * GEMM over K=(i,q)=9216.
// ---------------------------------------------------------------------------
__global__ __launch_bounds__(256) void s0_mfma_kernel(
    const _Float16* __restrict__ Xh, const _Float16* __restrict__ Wh,
    float* __restrict__ S0)
{
    const int wid  = blockIdx.x * 4 + (threadIdx.x >> 6);  // 0..1279
    const int lane = threadIdx.x & 63;
    const int bt  = wid / 80;
    const int rem = wid % 80;
    const int j   = rem >> 3;
    const int kc  = rem & 7;
    const int b0  = bt * 16;
    const int m    = lane & 15;
    const int quad = lane >> 4;
    const int ib   = kc * 144;

    const _Float16* ax = Xh + ((size_t)(b0 + m) * II + ib + quad) * QQ;
    const _Float16* bw = Wh + (((size_t)j * II + ib + quad) * PP + m) * QQ;

    f4 acc = {0.f, 0.f, 0.f, 0.f};
    for (int t = 0; t < 36; ++t) {
        const h8 a = *(const h8*)ax;
        const h8 b = *(const h8*)bw;
        acc = __builtin_amdgcn_mfma_f32_16x16x32_f16(a, b, acc, 0, 0, 0);
        ax += 4 * QQ;
        bw += (size_t)4 * PP * QQ;
    }
#pragma unroll
    for (int r = 0; r < 4; ++r)
        atomicAdd(&S0[((size_t)(b0 + quad * 4 + r) * JJ + j) * PP + m], 0.1f * acc[r]);
}

// ---------------------------------------------------------------------------
// Fused routing pass (R=1,2), LDS-fed, 2 b per thread (BT=32).
// Thread = (b_l 0..15, p). Batch A: b0+b_l; batch B: b0+b_l+16.
// Each W ds_read_b128 feeds BOTH batches' dot8 -> LDS-pipe issues halve vs
// R13 (the dominant ~16-20 us/pass term scales with block count).
// vv via DPP-squash of Sprev; R==1,it==0 persists v0; R==2 adds v0.
// Live regs ~100 (vv20+h20+e20+sacc20+misc) -> fits (256,4)=128 budget;
// spill tell: VGPR=64 + WRITE >> 23 MB (R6/R9/R14 failure signature).
// ---------------------------------------------------------------------------
template <int R>
__global__ __launch_bounds__(256, 4) void pass_kernel(
    const _Float16* __restrict__ Xh,  // [B][I][Q] f16
    const _Float16* __restrict__ Wh,  // [J][I][P][Q] f16
    const float* __restrict__ Sprev,  // [B][J][P]
    float* __restrict__ V0,           // v0 raw (R1 writes it==0, R2 reads)
    float* __restrict__ Sout)         // [B][J][P] pre-zeroed accumulator
{
    __shared__ _Float16 ws[JJ * WTILE];  // 20 KB
    __shared__ _Float16 xs[BT * XRH];    // 4.5 KB

    const int bt = blockIdx.x & (NBT - 1);
    const int it = blockIdx.x >> 3;
    const int b0 = bt * BT;
    const int i0 = it * IT;
    const int tid = threadIdx.x;

    // ---- stage W tile: 1280 h8 chunks, 5 per thread (coalesced 16B/lane)
    {
        const size_t jstride = (size_t)II * PP * QQ;
        const _Float16* wsrc = Wh + (size_t)i0 * PP * QQ;
#pragma unroll
        for (int k = 0; k < 5; ++k) {
            const int c = tid + k * 256;   // 0..1279
            const int j = c >> 7;          // 128 h8 chunks per j
            const int r = c & 127;
            *(h8*)(ws + j * WTILE + r * 8) = *(const h8*)(wsrc + j * jstride + r * 8);
        }
        // ---- stage x tile: 32 b x 8 h8 = 256 chunks, 1 per thread
        const int xb = tid >> 3;
        const int xr = tid & 7;
        *(h8*)(xs + xb * XRH + xr * 8) =
            *(const h8*)(Xh + ((size_t)(b0 + xb) * II + i0) * QQ + xr * 8);
    }
    __syncthreads();

    const int b_l = tid >> 4;           // 0..15
    const int p   = tid & 15;
    const int bA  = b0 + b_l;
    const int bB  = bA + 16;

    // inline squash of Sprev -> vv for both batches (pre-scaled by log2e)
    float vvA[JJ], vvB[JJ];
#pragma unroll
    for (int j = 0; j < JJ; ++j) {
        const float spA = Sprev[((size_t)bA * JJ + j) * PP + p];
        const float spB = Sprev[((size_t)bB * JJ + j) * PP + p];
        const float nA = row_sum16(spA * spA);
        const float nB = row_sum16(spB * spB);
        const float scA = nA * __builtin_amdgcn_rcpf(1.0f + nA)
                             * __builtin_amdgcn_rsqf(nA + 1e-7f);
        const float scB = nB * __builtin_amdgcn_rcpf(1.0f + nB)
                             * __builtin_amdgcn_rsqf(nB + 1e-7f);
        float vA = spA * scA;
        float vB = spB * scB;
        if (R == 1) {
            if (it == 0) {
                V0[((size_t)bA * JJ + j) * PP + p] = vA;
                V0[((size_t)bB * JJ + j) * PP + p] = vB;
            }
        } else {
            vA += V0[((size_t)bA * JJ + j) * PP + p];
            vB += V0[((size_t)bB * JJ + j) * PP + p];
        }
        vvA[j] = vA * LOG2E;
        vvB[j] = vB * LOG2E;
    }

    float saccA[JJ], saccB[JJ];
#pragma unroll
    for (int j = 0; j < JJ; ++j) { saccA[j] = 0.0f; saccB[j] = 0.0f; }

    const _Float16* wb = ws + p * QQ;    // single LDS base; imm offsets below
    const _Float16* xa = xs + b_l * XRH;
    const _Float16* xbp = xs + (b_l + 16) * XRH;

#pragma unroll
    for (int i = 0; i < IT; ++i) {
        const h8 x8A = *(const h8*)(xa + i * QQ);
        const h8 x8B = *(const h8*)(xbp + i * QQ);

        float hA[JJ], hB[JJ];
#pragma unroll
        for (int j = 0; j < JJ; ++j) {
            const h8 w8 = *(const h8*)(wb + j * WTILE + i * PP * QQ);  // shared read
            hA[j] = dot8(w8, x8A);
            hB[j] = dot8(w8, x8B);
        }

        float eA[JJ], eB[JJ];
#pragma unroll
        for (int j = 0; j < JJ; ++j) {
            const float bjA = row_sum16(vvA[j] * hA[j]);   // 2 indep DPP chains
            const float bjB = row_sum16(vvB[j] * hB[j]);
            eA[j] = __builtin_amdgcn_exp2f(bjA);
            eB[j] = __builtin_amdgcn_exp2f(bjB);
        }
        float aA0 = (eA[0] + eA[1]) + (eA[2] + eA[3]);
        float aA1 = (eA[4] + eA[5]) + (eA[6] + eA[7]);
        const float sumA = (aA0 + aA1) + (eA[8] + eA[9]);
        float aB0 = (eB[0] + eB[1]) + (eB[2] + eB[3]);
        float aB1 = (eB[4] + eB[5]) + (eB[6] + eB[7]);
        const float sumB = (aB0 + aB1) + (eB[8] + eB[9]);
        const float invA = __builtin_amdgcn_rcpf(sumA);
        const float invB = __builtin_amdgcn_rcpf(sumB);
#pragma unroll
        for (int j = 0; j < JJ; ++j) {
            saccA[j] += (eA[j] * invA) * hA[j];
            saccB[j] += (eB[j] * invB) * hB[j];
        }
    }

#pragma unroll
    for (int j = 0; j < JJ; ++j) {
        atomicAdd(&Sout[((size_t)bA * JJ + j) * PP + p], saccA[j]);
        atomicAdd(&Sout[((size_t)bB * JJ + j) * PP + p], saccB[j]);
    }
}

// ---------------------------------------------------------------------------
// final output squash (fp32 precise)
// ---------------------------------------------------------------------------
__global__ __launch_bounds__(256) void squash_out_kernel(const float* __restrict__ S,
                                                         float* __restrict__ V)
{
    const int idx = blockIdx.x * blockDim.x + threadIdx.x;  // (b*J + j)
    if (idx >= BB * JJ) return;
    const float4* sp = (const float4*)(S + idx * PP);
    float4 a = sp[0], b4 = sp[1], c4 = sp[2], d4 = sp[3];
    float s2 = a.x * a.x + a.y * a.y + a.z * a.z + a.w * a.w +
               b4.x * b4.x + b4.y * b4.y + b4.z * b4.z + b4.w * b4.w +
               c4.x * c4.x + c4.y * c4.y + c4.z * c4.z + c4.w * c4.w +
               d4.x * d4.x + d4.y * d4.y + d4.z * d4.z + d4.w * d4.w;
    const float scale = s2 / (1.0f + s2) / sqrtf(s2 + 1e-7f);
    a.x *= scale; a.y *= scale; a.z *= scale; a.w *= scale;
    b4.x *= scale; b4.y *= scale; b4.z *= scale; b4.w *= scale;
    c4.x *= scale; c4.y *= scale; c4.z *= scale; c4.w *= scale;
    d4.x *= scale; d4.y *= scale; d4.z *= scale; d4.w *= scale;
    float4* vp = (float4*)(V + idx * PP);
    vp[0] = a; vp[1] = b4; vp[2] = c4; vp[3] = d4;
}

extern "C" void kernel_launch(void* const* d_in, const int* in_sizes, int n_in,
                              void* d_out, int out_size, void* d_ws, size_t ws_size,
                              hipStream_t stream)
{
    const float* X = (const float*)d_in[0];  // [256][1152][8]
    const float* W = (const float*)d_in[1];  // [10][1152][16][8]
    float* out = (float*)d_out;              // [256][10][16]

    _Float16* Xh = (_Float16*)d_ws;          // NX halfs
    _Float16* Wh = Xh + NX;                  // NW halfs
    float* S0 = (float*)(Wh + NW);           // NS floats
    float* S1 = S0 + NS;
    float* S2 = S1 + NS;
    float* v0 = S2 + NS;                     // NS floats; total ~8.3 MB

    const int grid = NBT * NIT;              // 1152 blocks of 256 threads

    prep_kernel<<<1024, 256, 0, stream>>>(X, W, Xh, Wh, S0);
    s0_mfma_kernel<<<320, 256, 0, stream>>>(Xh, Wh, S0);
    pass_kernel<1><<<grid, 256, 0, stream>>>(Xh, Wh, S0, v0, S1);
    pass_kernel<2><<<grid, 256, 0, stream>>>(Xh, Wh, S1, v0, S2);
    squash_out_kernel<<<10, 256, 0, stream>>>(S2, out);
}